// Round 1
// baseline (220.004 us; speedup 1.0000x reference)
//
#include <hip/hip_runtime.h>
#include <hip/hip_bf16.h>

#define TT 512
#define HH 1024
#define EE 32
#define KK 4
#define II 512
#define SS 2048

using f32x4 = __attribute__((ext_vector_type(4))) float;
using s16x8 = __attribute__((ext_vector_type(8))) short;

__device__ __forceinline__ unsigned short f2bf(float f){
  unsigned int u = __builtin_bit_cast(unsigned int, f);
  u += 0x7fffu + ((u >> 16) & 1u);
  return (unsigned short)(u >> 16);
}

__device__ __forceinline__ uint4 pack8(const unsigned short* u){
  uint4 v;
  v.x = (unsigned)u[0] | ((unsigned)u[1] << 16);
  v.y = (unsigned)u[2] | ((unsigned)u[3] << 16);
  v.z = (unsigned)u[4] | ((unsigned)u[5] << 16);
  v.w = (unsigned)u[6] | ((unsigned)u[7] << 16);
  return v;
}

// ---------------- router: logits, top-4, weights, sigmoid gate, x->bf16 -----
__global__ __launch_bounds__(64) void k_router(
    const float* __restrict__ x, const float* __restrict__ Wg,
    unsigned short* __restrict__ xb, int* __restrict__ topk_idx,
    float* __restrict__ topk_w, float* __restrict__ sig_gate){
  int t = blockIdx.x; int l = threadIdx.x;
  const float* xr = x + (size_t)t * HH;
  #pragma unroll
  for(int i=0;i<HH/64;i++){
    int h = l + 64*i;
    xb[(size_t)t*HH + h] = f2bf(xr[h]);
  }
  float acc0=0.f, acc1=0.f, acc2=0.f, acc3=0.f;
  if(l < EE+1){
    const float* wcol = Wg + l;
    for(int h=0; h<HH; h+=4){
      acc0 += xr[h]   * wcol[(size_t)h*(EE+1)];
      acc1 += xr[h+1] * wcol[(size_t)(h+1)*(EE+1)];
      acc2 += xr[h+2] * wcol[(size_t)(h+2)*(EE+1)];
      acc3 += xr[h+3] * wcol[(size_t)(h+3)*(EE+1)];
    }
  }
  __shared__ float lg[EE+1];
  if(l < EE+1) lg[l] = (acc0+acc1)+(acc2+acc3);
  __syncthreads();
  if(l == 0){
    float v[EE];
    #pragma unroll
    for(int i=0;i<EE;i++) v[i]=lg[i];
    int idx[KK]; float val[KK];
    #pragma unroll
    for(int k=0;k<KK;k++){
      float m=-1e30f; int mi=0;
      for(int i=0;i<EE;i++){ if(v[i]>m){ m=v[i]; mi=i; } }
      idx[k]=mi; val[k]=m; v[mi]=-1e30f;
    }
    float mx = val[0], s=0.f; float w[KK];
    #pragma unroll
    for(int k=0;k<KK;k++){ w[k]=__expf(val[k]-mx); s+=w[k]; }
    float inv = 1.f/s;
    #pragma unroll
    for(int k=0;k<KK;k++){ topk_idx[t*KK+k]=idx[k]; topk_w[t*KK+k]=w[k]*inv; }
    sig_gate[t] = 1.f/(1.f+__expf(-lg[EE]));
  }
}

// ---------------- per-expert token list (deterministic compaction) ----------
__global__ __launch_bounds__(64) void k_build(
    const int* __restrict__ topk_idx, const float* __restrict__ topk_w,
    int* __restrict__ token_list, float* __restrict__ weight_list,
    int* __restrict__ counts){
  int e = blockIdx.x; int l = threadIdx.x;
  int cnt = 0;
  for(int c=0;c<TT;c+=64){
    int t = c + l;
    int kk = -1;
    #pragma unroll
    for(int k=0;k<KK;k++) if(topk_idx[t*KK+k]==e) kk=k;
    unsigned long long b = __ballot(kk>=0);
    int pre = __popcll(b & ((1ull<<l)-1ull));
    if(kk>=0){
      token_list[e*TT + cnt + pre] = t;
      weight_list[e*TT + cnt + pre] = topk_w[t*KK+kk];
    }
    cnt += __popcll(b);
  }
  if(l==0) counts[e]=cnt;
}

// ---------------- staging helpers ------------------------------------------
// LDS tiles are [64][40] ushorts (pitch 80B) — bank-balanced for b128 ops.
__device__ __forceinline__ void stage_a(
    unsigned short As[64][40], const unsigned short* __restrict__ A, int lda, int tid){
  int r = tid >> 2, seg = tid & 3;
  uint4 v = *reinterpret_cast<const uint4*>(A + (size_t)r*lda + seg*8);
  *reinterpret_cast<uint4*>(&As[r][seg*8]) = v;
}

__device__ __forceinline__ void stage_a_gather(
    unsigned short As[64][40], const unsigned short* __restrict__ A, int lda,
    const int* __restrict__ rows, int nv, int k0, int tid){
  int r = tid >> 2, seg = tid & 3;
  uint4 v = make_uint4(0,0,0,0);
  if(r < nv){
    int row = rows[r];
    v = *reinterpret_cast<const uint4*>(A + (size_t)row*lda + k0 + seg*8);
  }
  *reinterpret_cast<uint4*>(&As[r][seg*8]) = v;
}

__device__ __forceinline__ void stage_a_clamp(
    unsigned short As[64][40], const unsigned short* __restrict__ A, int lda,
    int r0, int nv, int k0, int tid){
  int r = tid >> 2, seg = tid & 3;
  uint4 v = make_uint4(0,0,0,0);
  if(r < nv) v = *reinterpret_cast<const uint4*>(A + (size_t)(r0+r)*lda + k0 + seg*8);
  *reinterpret_cast<uint4*>(&As[r][seg*8]) = v;
}

// B is fp32 row-major (K x N); stage 32x64 tile TRANSPOSED (Bs[n][k]) as bf16.
__device__ __forceinline__ void stage_bt(
    unsigned short Bs[64][40], const float* __restrict__ B, int ldb, int tid){
  int n = tid & 63, kh = tid >> 6;
  const float* p = B + (size_t)(kh*8)*ldb + n;
  unsigned short u[8];
  #pragma unroll
  for(int i=0;i<8;i++) u[i] = f2bf(p[(size_t)i*ldb]);
  *reinterpret_cast<uint4*>(&Bs[n][kh*8]) = pack8(u);
}

// ---------------- shared expert: h = silu(x@Wsg) * (x@Wsu) ------------------
__global__ __launch_bounds__(256) void k_shared_gateup(
    const unsigned short* __restrict__ xb, const float* __restrict__ Wsg,
    const float* __restrict__ Wsu, unsigned short* __restrict__ Hs){
  __shared__ unsigned short As[64][40];
  __shared__ unsigned short Bg[64][40];
  __shared__ unsigned short Bu[64][40];
  int n0 = blockIdx.x * 64, r0 = blockIdx.y * 64;
  int tid = threadIdx.x, w = tid >> 6, l = tid & 63;
  f32x4 zero = {0.f,0.f,0.f,0.f};
  f32x4 ag[4] = {zero,zero,zero,zero};
  f32x4 au[4] = {zero,zero,zero,zero};
  for(int k0=0;k0<HH;k0+=32){
    stage_a(As, xb + (size_t)r0*HH + k0, HH, tid);
    stage_bt(Bg, Wsg + (size_t)k0*SS + n0, SS, tid);
    stage_bt(Bu, Wsu + (size_t)k0*SS + n0, SS, tid);
    __syncthreads();
    int kt = l >> 4, mm = l & 15;
    s16x8 af = *reinterpret_cast<const s16x8*>(&As[w*16 + mm][kt*8]);
    #pragma unroll
    for(int c=0;c<4;c++){
      s16x8 bg = *reinterpret_cast<const s16x8*>(&Bg[c*16 + mm][kt*8]);
      s16x8 bu = *reinterpret_cast<const s16x8*>(&Bu[c*16 + mm][kt*8]);
      ag[c] = __builtin_amdgcn_mfma_f32_16x16x32_bf16(af, bg, ag[c], 0,0,0);
      au[c] = __builtin_amdgcn_mfma_f32_16x16x32_bf16(af, bu, au[c], 0,0,0);
    }
    __syncthreads();
  }
  int mm = l & 15;
  int rb = r0 + w*16 + (l>>4)*4;
  #pragma unroll
  for(int c=0;c<4;c++){
    #pragma unroll
    for(int j=0;j<4;j++){
      float g = ag[c][j], u = au[c][j];
      float h = g * u / (1.f + __expf(-g));
      Hs[(size_t)(rb+j)*SS + n0 + c*16 + mm] = f2bf(h);
    }
  }
}

// ---------------- shared expert down: out = sigmoid(gate) * (Hs @ Wsd) ------
__global__ __launch_bounds__(256) void k_shared_down(
    const unsigned short* __restrict__ Hsrc, const float* __restrict__ Wsd,
    const float* __restrict__ sig_gate, float* __restrict__ out){
  __shared__ unsigned short As[64][40];
  __shared__ unsigned short Bs[64][40];
  int n0 = blockIdx.x * 64, r0 = blockIdx.y * 64;
  int tid = threadIdx.x, w = tid>>6, l = tid&63;
  f32x4 zero = {0.f,0.f,0.f,0.f};
  f32x4 acc[4] = {zero,zero,zero,zero};
  for(int k0=0;k0<SS;k0+=32){
    stage_a(As, Hsrc + (size_t)r0*SS + k0, SS, tid);
    stage_bt(Bs, Wsd + (size_t)k0*HH + n0, HH, tid);
    __syncthreads();
    int kt=l>>4, mm=l&15;
    s16x8 af = *reinterpret_cast<const s16x8*>(&As[w*16+mm][kt*8]);
    #pragma unroll
    for(int c=0;c<4;c++){
      s16x8 bf = *reinterpret_cast<const s16x8*>(&Bs[c*16+mm][kt*8]);
      acc[c] = __builtin_amdgcn_mfma_f32_16x16x32_bf16(af, bf, acc[c],0,0,0);
    }
    __syncthreads();
  }
  int mm=l&15, rb = r0 + w*16 + (l>>4)*4;
  #pragma unroll
  for(int c=0;c<4;c++){
    #pragma unroll
    for(int j=0;j<4;j++){
      out[(size_t)(rb+j)*HH + n0 + c*16 + mm] = sig_gate[rb+j] * acc[c][j];
    }
  }
}

// ---------------- routed experts: h_e = silu(Xe@Wg_e)*(Xe@Wu_e) -------------
__global__ __launch_bounds__(256) void k_expert_gateup(
    const unsigned short* __restrict__ xb, const float* __restrict__ Wgate,
    const float* __restrict__ Wup, const int* __restrict__ token_list,
    const int* __restrict__ counts, unsigned short* __restrict__ hbuf){
  int e = blockIdx.y;
  int cnt = counts[e];
  if(cnt == 0) return;
  int off = 0;
  for(int i=0;i<e;i++) off += counts[i];
  int i0 = blockIdx.x * 64;
  int tid = threadIdx.x, w=tid>>6, l=tid&63;
  const float* Bg0 = Wgate + (size_t)e*HH*II;
  const float* Bu0 = Wup   + (size_t)e*HH*II;
  __shared__ unsigned short As[64][40];
  __shared__ unsigned short Bg[64][40];
  __shared__ unsigned short Bu[64][40];
  for(int rt=0; rt*64<cnt; rt++){
    int nv = cnt - rt*64; if(nv > 64) nv = 64;
    const int* rows = token_list + e*TT + rt*64;
    f32x4 zero={0.f,0.f,0.f,0.f};
    f32x4 ag[4]={zero,zero,zero,zero}, au[4]={zero,zero,zero,zero};
    for(int k0=0;k0<HH;k0+=32){
      stage_a_gather(As, xb, HH, rows, nv, k0, tid);
      stage_bt(Bg, Bg0 + (size_t)k0*II + i0, II, tid);
      stage_bt(Bu, Bu0 + (size_t)k0*II + i0, II, tid);
      __syncthreads();
      int kt=l>>4, mm=l&15;
      s16x8 af = *reinterpret_cast<const s16x8*>(&As[w*16+mm][kt*8]);
      #pragma unroll
      for(int c=0;c<4;c++){
        s16x8 bg = *reinterpret_cast<const s16x8*>(&Bg[c*16+mm][kt*8]);
        s16x8 bu = *reinterpret_cast<const s16x8*>(&Bu[c*16+mm][kt*8]);
        ag[c]=__builtin_amdgcn_mfma_f32_16x16x32_bf16(af,bg,ag[c],0,0,0);
        au[c]=__builtin_amdgcn_mfma_f32_16x16x32_bf16(af,bu,au[c],0,0,0);
      }
      __syncthreads();
    }
    int mm=l&15; int rr0 = w*16 + (l>>4)*4;
    #pragma unroll
    for(int c=0;c<4;c++){
      #pragma unroll
      for(int j=0;j<4;j++){
        int rr = rr0 + j;
        if(rr < nv){
          float g=ag[c][j], u=au[c][j];
          float h = g*u/(1.f+__expf(-g));
          hbuf[(size_t)(off+rt*64+rr)*II + i0 + c*16 + mm] = f2bf(h);
        }
      }
    }
  }
}

// ---------------- routed experts down: out += w * (h_e @ Wd_e) --------------
__global__ __launch_bounds__(256) void k_expert_down(
    const unsigned short* __restrict__ hbuf, const float* __restrict__ Wdown,
    const int* __restrict__ token_list, const float* __restrict__ weight_list,
    const int* __restrict__ counts, float* __restrict__ out){
  int e = blockIdx.y;
  int cnt = counts[e]; if(cnt==0) return;
  int off=0; for(int i=0;i<e;i++) off += counts[i];
  int n0 = blockIdx.x * 64;
  int tid=threadIdx.x, w=tid>>6, l=tid&63;
  const float* B0 = Wdown + (size_t)e*II*HH;
  __shared__ unsigned short As[64][40];
  __shared__ unsigned short Bs[64][40];
  for(int rt=0; rt*64<cnt; rt++){
    int nv = cnt - rt*64; if(nv > 64) nv = 64;
    f32x4 zero={0.f,0.f,0.f,0.f};
    f32x4 acc[4]={zero,zero,zero,zero};
    for(int k0=0;k0<II;k0+=32){
      stage_a_clamp(As, hbuf, II, off+rt*64, nv, k0, tid);
      stage_bt(Bs, B0 + (size_t)k0*HH + n0, HH, tid);
      __syncthreads();
      int kt=l>>4, mm=l&15;
      s16x8 af = *reinterpret_cast<const s16x8*>(&As[w*16+mm][kt*8]);
      #pragma unroll
      for(int c=0;c<4;c++){
        s16x8 bf = *reinterpret_cast<const s16x8*>(&Bs[c*16+mm][kt*8]);
        acc[c]=__builtin_amdgcn_mfma_f32_16x16x32_bf16(af,bf,acc[c],0,0,0);
      }
      __syncthreads();
    }
    int mm=l&15; int rr0=w*16+(l>>4)*4;
    #pragma unroll
    for(int c=0;c<4;c++){
      #pragma unroll
      for(int j=0;j<4;j++){
        int rr=rr0+j;
        if(rr<nv){
          int t = token_list[e*TT + rt*64 + rr];
          float wt = weight_list[e*TT + rt*64 + rr];
          atomicAdd(&out[(size_t)t*HH + n0 + c*16 + mm], wt * acc[c][j]);
        }
      }
    }
  }
}

extern "C" void kernel_launch(void* const* d_in, const int* in_sizes, int n_in,
                              void* d_out, int out_size, void* d_ws, size_t ws_size,
                              hipStream_t stream) {
  const float* x     = (const float*)d_in[0];
  const float* Wg    = (const float*)d_in[1];
  const float* Wgate = (const float*)d_in[2];
  const float* Wup   = (const float*)d_in[3];
  const float* Wdown = (const float*)d_in[4];
  const float* Wsg   = (const float*)d_in[5];
  const float* Wsu   = (const float*)d_in[6];
  const float* Wsd   = (const float*)d_in[7];
  float* out = (float*)d_out;

  char* ws = (char*)d_ws;
  unsigned short* xb   = (unsigned short*)ws; ws += (size_t)TT*HH*2;       // 1 MB
  unsigned short* Hs   = (unsigned short*)ws; ws += (size_t)TT*SS*2;       // 2 MB
  unsigned short* hbuf = (unsigned short*)ws; ws += (size_t)(TT*KK+64)*II*2; // ~2.1 MB
  int*   token_list  = (int*)ws;   ws += (size_t)EE*TT*4;
  float* weight_list = (float*)ws; ws += (size_t)EE*TT*4;
  int*   topk_idx    = (int*)ws;   ws += (size_t)TT*KK*4;
  float* topk_wq     = (float*)ws; ws += (size_t)TT*KK*4;
  int*   counts      = (int*)ws;   ws += 128;
  float* sig_gate    = (float*)ws; ws += (size_t)TT*4;

  k_router<<<TT, 64, 0, stream>>>(x, Wg, xb, topk_idx, topk_wq, sig_gate);
  k_build<<<EE, 64, 0, stream>>>(topk_idx, topk_wq, token_list, weight_list, counts);
  k_shared_gateup<<<dim3(SS/64, TT/64), 256, 0, stream>>>(xb, Wsg, Wsu, Hs);
  k_expert_gateup<<<dim3(II/64, EE), 256, 0, stream>>>(xb, Wgate, Wup, token_list, counts, hbuf);
  k_shared_down<<<dim3(HH/64, TT/64), 256, 0, stream>>>(Hs, Wsd, sig_gate, out);
  k_expert_down<<<dim3(HH/64, EE), 256, 0, stream>>>(hbuf, Wdown, token_list, weight_list, counts, out);
}

// Round 2
// 146.524 us; speedup vs baseline: 1.5015x; 1.5015x over previous
//
#include <hip/hip_runtime.h>
#include <hip/hip_bf16.h>

#define TT 512
#define HH 1024
#define EE 32
#define KK 4
#define II 512
#define SS 2048

using f32x4 = __attribute__((ext_vector_type(4))) float;
using s16x8 = __attribute__((ext_vector_type(8))) short;

__device__ __forceinline__ unsigned short f2bf(float f){
  unsigned int u = __builtin_bit_cast(unsigned int, f);
  u += 0x7fffu + ((u >> 16) & 1u);
  return (unsigned short)(u >> 16);
}

__device__ __forceinline__ uint4 pack8(const unsigned short* u){
  uint4 v;
  v.x = (unsigned)u[0] | ((unsigned)u[1] << 16);
  v.y = (unsigned)u[2] | ((unsigned)u[3] << 16);
  v.z = (unsigned)u[4] | ((unsigned)u[5] << 16);
  v.w = (unsigned)u[6] | ((unsigned)u[7] << 16);
  return v;
}

// ---------------- router: logits, top-4, weights, sigmoid gate, x->bf16 -----
__global__ __launch_bounds__(64) void k_router(
    const float* __restrict__ x, const float* __restrict__ Wg,
    unsigned short* __restrict__ xb, int* __restrict__ topk_idx,
    float* __restrict__ topk_w, float* __restrict__ sig_gate){
  int t = blockIdx.x; int l = threadIdx.x;
  const float* xr = x + (size_t)t * HH;
  #pragma unroll
  for(int i=0;i<HH/64;i++){
    int h = l + 64*i;
    xb[(size_t)t*HH + h] = f2bf(xr[h]);
  }
  float acc0=0.f, acc1=0.f, acc2=0.f, acc3=0.f;
  if(l < EE+1){
    const float* wcol = Wg + l;
    for(int h=0; h<HH; h+=4){
      acc0 += xr[h]   * wcol[(size_t)h*(EE+1)];
      acc1 += xr[h+1] * wcol[(size_t)(h+1)*(EE+1)];
      acc2 += xr[h+2] * wcol[(size_t)(h+2)*(EE+1)];
      acc3 += xr[h+3] * wcol[(size_t)(h+3)*(EE+1)];
    }
  }
  __shared__ float lg[EE+1];
  if(l < EE+1) lg[l] = (acc0+acc1)+(acc2+acc3);
  __syncthreads();
  if(l == 0){
    float v[EE];
    #pragma unroll
    for(int i=0;i<EE;i++) v[i]=lg[i];
    int idx[KK]; float val[KK];
    #pragma unroll
    for(int k=0;k<KK;k++){
      float m=-1e30f; int mi=0;
      for(int i=0;i<EE;i++){ if(v[i]>m){ m=v[i]; mi=i; } }
      idx[k]=mi; val[k]=m; v[mi]=-1e30f;
    }
    float mx = val[0], s=0.f; float w[KK];
    #pragma unroll
    for(int k=0;k<KK;k++){ w[k]=__expf(val[k]-mx); s+=w[k]; }
    float inv = 1.f/s;
    #pragma unroll
    for(int k=0;k<KK;k++){ topk_idx[t*KK+k]=idx[k]; topk_w[t*KK+k]=w[k]*inv; }
    sig_gate[t] = 1.f/(1.f+__expf(-lg[EE]));
  }
}

// ---------------- per-expert token list (deterministic compaction) ----------
__global__ __launch_bounds__(64) void k_build(
    const int* __restrict__ topk_idx, const float* __restrict__ topk_w,
    int* __restrict__ token_list, float* __restrict__ weight_list,
    int* __restrict__ counts){
  int e = blockIdx.x; int l = threadIdx.x;
  int cnt = 0;
  for(int c=0;c<TT;c+=64){
    int t = c + l;
    int kk = -1;
    #pragma unroll
    for(int k=0;k<KK;k++) if(topk_idx[t*KK+k]==e) kk=k;
    unsigned long long b = __ballot(kk>=0);
    int pre = __popcll(b & ((1ull<<l)-1ull));
    if(kk>=0){
      token_list[e*TT + cnt + pre] = t;
      weight_list[e*TT + cnt + pre] = topk_w[t*KK+kk];
    }
    cnt += __popcll(b);
  }
  if(l==0) counts[e]=cnt;
}

// ---------------- staging helpers (LDS tiles [64][40], pitch 80B) ----------
__device__ __forceinline__ void wrb(unsigned short B[64][40], const float* f,
                                    int n, int kh){
  unsigned short u[8];
  #pragma unroll
  for(int i=0;i<8;i++) u[i] = f2bf(f[i]);
  *reinterpret_cast<uint4*>(&B[n][kh*8]) = pack8(u);
}

// Double-buffered dual-B GEMM body: acc{g,u} += A(64xK) * {Bg,Bu}(Kx64).
// Ap: this thread's A source (row ar=tid>>2, seg as=tid&3), advances 32/step.
// Gp/Up: this thread's B source (row kh*8, col n), advances 32*ldb/step.
__device__ __forceinline__ void gemm_dual(
    const unsigned short* Ap, bool va,
    const float* Gp, const float* Up, int ldb, int NK,
    f32x4* ag, f32x4* au,
    unsigned short As[2][64][40], unsigned short Bg[2][64][40],
    unsigned short Bu[2][64][40], int tid){
  int w = tid>>6, l = tid&63;
  int n = tid&63, kh = tid>>6, ar = tid>>2, as_ = tid&3;
  uint4 av = make_uint4(0,0,0,0);
  float gv[8], uv[8];
  if(va) av = *reinterpret_cast<const uint4*>(Ap);
  #pragma unroll
  for(int i=0;i<8;i++){ gv[i]=Gp[(size_t)i*ldb]; uv[i]=Up[(size_t)i*ldb]; }
  *reinterpret_cast<uint4*>(&As[0][ar][as_*8]) = av;
  wrb(Bg[0], gv, n, kh); wrb(Bu[0], uv, n, kh);
  __syncthreads();
  for(int ks=0; ks<NK; ks++){
    int cur = ks & 1;
    bool more = (ks+1 < NK);
    if(more){
      av = make_uint4(0,0,0,0);
      if(va) av = *reinterpret_cast<const uint4*>(Ap + (size_t)(ks+1)*32);
      const float* g2 = Gp + (size_t)(ks+1)*32*ldb;
      const float* u2 = Up + (size_t)(ks+1)*32*ldb;
      #pragma unroll
      for(int i=0;i<8;i++){ gv[i]=g2[(size_t)i*ldb]; uv[i]=u2[(size_t)i*ldb]; }
    }
    int kt = l>>4, mm = l&15;
    s16x8 af = *reinterpret_cast<const s16x8*>(&As[cur][w*16+mm][kt*8]);
    #pragma unroll
    for(int c=0;c<4;c++){
      s16x8 b0 = *reinterpret_cast<const s16x8*>(&Bg[cur][c*16+mm][kt*8]);
      s16x8 b1 = *reinterpret_cast<const s16x8*>(&Bu[cur][c*16+mm][kt*8]);
      ag[c] = __builtin_amdgcn_mfma_f32_16x16x32_bf16(af, b0, ag[c], 0,0,0);
      au[c] = __builtin_amdgcn_mfma_f32_16x16x32_bf16(af, b1, au[c], 0,0,0);
    }
    if(more){
      int nx = cur^1;
      *reinterpret_cast<uint4*>(&As[nx][ar][as_*8]) = av;
      wrb(Bg[nx], gv, n, kh); wrb(Bu[nx], uv, n, kh);
    }
    __syncthreads();
  }
}

// Single-B variant for the down projections.
__device__ __forceinline__ void gemm_single(
    const unsigned short* Ap, bool va,
    const float* Bp, int ldb, int NK, f32x4* acc,
    unsigned short As[2][64][40], unsigned short Bs[2][64][40], int tid){
  int w = tid>>6, l = tid&63;
  int n = tid&63, kh = tid>>6, ar = tid>>2, as_ = tid&3;
  uint4 av = make_uint4(0,0,0,0);
  float bv[8];
  if(va) av = *reinterpret_cast<const uint4*>(Ap);
  #pragma unroll
  for(int i=0;i<8;i++) bv[i] = Bp[(size_t)i*ldb];
  *reinterpret_cast<uint4*>(&As[0][ar][as_*8]) = av;
  wrb(Bs[0], bv, n, kh);
  __syncthreads();
  for(int ks=0; ks<NK; ks++){
    int cur = ks & 1;
    bool more = (ks+1 < NK);
    if(more){
      av = make_uint4(0,0,0,0);
      if(va) av = *reinterpret_cast<const uint4*>(Ap + (size_t)(ks+1)*32);
      const float* b2 = Bp + (size_t)(ks+1)*32*ldb;
      #pragma unroll
      for(int i=0;i<8;i++) bv[i] = b2[(size_t)i*ldb];
    }
    int kt = l>>4, mm = l&15;
    s16x8 af = *reinterpret_cast<const s16x8*>(&As[cur][w*16+mm][kt*8]);
    #pragma unroll
    for(int c=0;c<4;c++){
      s16x8 b0 = *reinterpret_cast<const s16x8*>(&Bs[cur][c*16+mm][kt*8]);
      acc[c] = __builtin_amdgcn_mfma_f32_16x16x32_bf16(af, b0, acc[c], 0,0,0);
    }
    if(more){
      int nx = cur^1;
      *reinterpret_cast<uint4*>(&As[nx][ar][as_*8]) = av;
      wrb(Bs[nx], bv, n, kh);
    }
    __syncthreads();
  }
}

// ---------------- phase 2: ALL gate-up (shared + routed) in one launch ------
__global__ __launch_bounds__(256) void k_gateup_all(
    const unsigned short* __restrict__ xb,
    const float* __restrict__ Wsg, const float* __restrict__ Wsu,
    unsigned short* __restrict__ Hs,
    const float* __restrict__ Wgate, const float* __restrict__ Wup,
    const int* __restrict__ token_list, const int* __restrict__ counts,
    unsigned short* __restrict__ hbuf){
  __shared__ unsigned short As[2][64][40];
  __shared__ unsigned short Bg[2][64][40];
  __shared__ unsigned short Bu[2][64][40];
  int tid = threadIdx.x, w = tid>>6, l = tid&63;
  int n = tid&63, kh = tid>>6, ar = tid>>2, as_ = tid&3;
  int bid = blockIdx.x;
  f32x4 zero = {0.f,0.f,0.f,0.f};
  const int NSH = (SS/64)*(TT/64);   // 256 shared blocks

  if(bid < NSH){
    int n0 = (bid & (SS/64 - 1)) * 64;
    int r0 = (bid / (SS/64)) * 64;
    f32x4 ag[4]={zero,zero,zero,zero}, au[4]={zero,zero,zero,zero};
    const unsigned short* Ap = xb + (size_t)(r0+ar)*HH + as_*8;
    const float* Gp = Wsg + (size_t)(kh*8)*SS + n0 + n;
    const float* Up = Wsu + (size_t)(kh*8)*SS + n0 + n;
    gemm_dual(Ap, true, Gp, Up, SS, HH/32, ag, au, As, Bg, Bu, tid);
    int mm = l&15, rb = r0 + w*16 + (l>>4)*4;
    #pragma unroll
    for(int c=0;c<4;c++){
      #pragma unroll
      for(int j=0;j<4;j++){
        float g = ag[c][j], u = au[c][j];
        Hs[(size_t)(rb+j)*SS + n0 + c*16 + mm] = f2bf(g*u/(1.f+__expf(-g)));
      }
    }
  } else {
    int b = bid - NSH;
    int e = b >> 3;            // II/64 = 8
    int i0 = (b & 7) * 64;
    int cnt = counts[e]; if(cnt == 0) return;
    int off = 0;
    for(int i=0;i<e;i++) off += counts[i];
    const float* Bg0 = Wgate + (size_t)e*HH*II;
    const float* Bu0 = Wup   + (size_t)e*HH*II;
    for(int rt=0; rt*64<cnt; rt++){
      int nv = cnt - rt*64; if(nv > 64) nv = 64;
      const int* rows = token_list + e*TT + rt*64;
      int arow = (ar < nv) ? rows[ar] : 0;
      bool va = ar < nv;
      f32x4 ag[4]={zero,zero,zero,zero}, au[4]={zero,zero,zero,zero};
      const unsigned short* Ap = xb + (size_t)arow*HH + as_*8;
      const float* Gp = Bg0 + (size_t)(kh*8)*II + i0 + n;
      const float* Up = Bu0 + (size_t)(kh*8)*II + i0 + n;
      gemm_dual(Ap, va, Gp, Up, II, HH/32, ag, au, As, Bg, Bu, tid);
      int mm = l&15, rr0 = w*16 + (l>>4)*4;
      #pragma unroll
      for(int c=0;c<4;c++){
        #pragma unroll
        for(int j=0;j<4;j++){
          int rr = rr0 + j;
          if(rr < nv){
            float g = ag[c][j], u = au[c][j];
            hbuf[(size_t)(off+rt*64+rr)*II + i0 + c*16 + mm] =
                f2bf(g*u/(1.f+__expf(-g)));
          }
        }
      }
    }
  }
}

// ---------------- phase 3: ALL down (shared + routed), atomic into out ------
__global__ __launch_bounds__(256) void k_down_all(
    const unsigned short* __restrict__ Hsrc, const float* __restrict__ Wsd,
    const float* __restrict__ sig_gate,
    const unsigned short* __restrict__ hbuf, const float* __restrict__ Wdown,
    const int* __restrict__ token_list, const float* __restrict__ weight_list,
    const int* __restrict__ counts, float* __restrict__ out){
  __shared__ unsigned short As[2][64][40];
  __shared__ unsigned short Bs[2][64][40];
  int tid = threadIdx.x, w = tid>>6, l = tid&63;
  int n = tid&63, kh = tid>>6, ar = tid>>2, as_ = tid&3;
  int bid = blockIdx.x;
  f32x4 zero = {0.f,0.f,0.f,0.f};
  const int NSH = (HH/64)*(TT/64);   // 128 shared blocks

  if(bid < NSH){
    int n0 = (bid & (HH/64 - 1)) * 64;
    int r0 = (bid / (HH/64)) * 64;
    f32x4 acc[4]={zero,zero,zero,zero};
    const unsigned short* Ap = Hsrc + (size_t)(r0+ar)*SS + as_*8;
    const float* Bp = Wsd + (size_t)(kh*8)*HH + n0 + n;
    gemm_single(Ap, true, Bp, HH, SS/32, acc, As, Bs, tid);
    int mm = l&15, rb = r0 + w*16 + (l>>4)*4;
    #pragma unroll
    for(int c=0;c<4;c++){
      #pragma unroll
      for(int j=0;j<4;j++){
        atomicAdd(&out[(size_t)(rb+j)*HH + n0 + c*16 + mm],
                  sig_gate[rb+j]*acc[c][j]);
      }
    }
  } else {
    int b = bid - NSH;
    int e = b >> 4;            // HH/64 = 16
    int n0 = (b & 15) * 64;
    int cnt = counts[e]; if(cnt == 0) return;
    int off = 0;
    for(int i=0;i<e;i++) off += counts[i];
    const float* B0 = Wdown + (size_t)e*II*HH;
    for(int rt=0; rt*64<cnt; rt++){
      int nv = cnt - rt*64; if(nv > 64) nv = 64;
      bool va = ar < nv;
      f32x4 acc[4]={zero,zero,zero,zero};
      const unsigned short* Ap = hbuf + (size_t)(off+rt*64+ar)*II + as_*8;
      const float* Bp = B0 + (size_t)(kh*8)*HH + n0 + n;
      gemm_single(Ap, va, Bp, HH, II/32, acc, As, Bs, tid);
      int mm = l&15, rr0 = w*16 + (l>>4)*4;
      #pragma unroll
      for(int c=0;c<4;c++){
        #pragma unroll
        for(int j=0;j<4;j++){
          int rr = rr0 + j;
          if(rr < nv){
            int t = token_list[e*TT + rt*64 + rr];
            float wt = weight_list[e*TT + rt*64 + rr];
            atomicAdd(&out[(size_t)t*HH + n0 + c*16 + mm], wt*acc[c][j]);
          }
        }
      }
    }
  }
}

extern "C" void kernel_launch(void* const* d_in, const int* in_sizes, int n_in,
                              void* d_out, int out_size, void* d_ws, size_t ws_size,
                              hipStream_t stream) {
  const float* x     = (const float*)d_in[0];
  const float* Wg    = (const float*)d_in[1];
  const float* Wgate = (const float*)d_in[2];
  const float* Wup   = (const float*)d_in[3];
  const float* Wdown = (const float*)d_in[4];
  const float* Wsg   = (const float*)d_in[5];
  const float* Wsu   = (const float*)d_in[6];
  const float* Wsd   = (const float*)d_in[7];
  float* out = (float*)d_out;

  char* ws = (char*)d_ws;
  unsigned short* xb   = (unsigned short*)ws; ws += (size_t)TT*HH*2;
  unsigned short* Hs   = (unsigned short*)ws; ws += (size_t)TT*SS*2;
  unsigned short* hbuf = (unsigned short*)ws; ws += (size_t)(TT*KK+64)*II*2;
  int*   token_list  = (int*)ws;   ws += (size_t)EE*TT*4;
  float* weight_list = (float*)ws; ws += (size_t)EE*TT*4;
  int*   topk_idx    = (int*)ws;   ws += (size_t)TT*KK*4;
  float* topk_wq     = (float*)ws; ws += (size_t)TT*KK*4;
  int*   counts      = (int*)ws;   ws += 128;
  float* sig_gate    = (float*)ws; ws += (size_t)TT*4;

  hipMemsetAsync(d_out, 0, (size_t)TT*HH*4, stream);
  k_router<<<TT, 64, 0, stream>>>(x, Wg, xb, topk_idx, topk_wq, sig_gate);
  k_build<<<EE, 64, 0, stream>>>(topk_idx, topk_wq, token_list, weight_list, counts);
  k_gateup_all<<<(SS/64)*(TT/64) + EE*(II/64), 256, 0, stream>>>(
      xb, Wsg, Wsu, Hs, Wgate, Wup, token_list, counts, hbuf);
  k_down_all<<<(HH/64)*(TT/64) + EE*(HH/64), 256, 0, stream>>>(
      Hs, Wsd, sig_gate, hbuf, Wdown, token_list, weight_list, counts, out);
}

// Round 3
// 139.769 us; speedup vs baseline: 1.5741x; 1.0483x over previous
//
#include <hip/hip_runtime.h>
#include <hip/hip_bf16.h>

#define TT 512
#define HH 1024
#define EE 32
#define KK 4
#define II 512
#define SS 2048

using f32x4 = __attribute__((ext_vector_type(4))) float;
using s16x8 = __attribute__((ext_vector_type(8))) short;

__device__ __forceinline__ unsigned short f2bf(float f){
  unsigned int u = __builtin_bit_cast(unsigned int, f);
  u += 0x7fffu + ((u >> 16) & 1u);
  return (unsigned short)(u >> 16);
}

// ---------------- router: logits, top-4, weights, sigmoid gate, x->bf16 -----
__global__ __launch_bounds__(64) void k_router(
    const float* __restrict__ x, const float* __restrict__ Wg,
    unsigned short* __restrict__ xb, int* __restrict__ topk_idx,
    float* __restrict__ topk_w, float* __restrict__ sig_gate){
  int t = blockIdx.x; int l = threadIdx.x;
  const float* xr = x + (size_t)t * HH;
  #pragma unroll
  for(int i=0;i<HH/64;i++){
    int h = l + 64*i;
    xb[(size_t)t*HH + h] = f2bf(xr[h]);
  }
  float acc0=0.f, acc1=0.f, acc2=0.f, acc3=0.f;
  if(l < EE+1){
    const float* wcol = Wg + l;
    for(int h=0; h<HH; h+=4){
      acc0 += xr[h]   * wcol[(size_t)h*(EE+1)];
      acc1 += xr[h+1] * wcol[(size_t)(h+1)*(EE+1)];
      acc2 += xr[h+2] * wcol[(size_t)(h+2)*(EE+1)];
      acc3 += xr[h+3] * wcol[(size_t)(h+3)*(EE+1)];
    }
  }
  __shared__ float lg[EE+1];
  if(l < EE+1) lg[l] = (acc0+acc1)+(acc2+acc3);
  __syncthreads();
  if(l == 0){
    float v[EE];
    #pragma unroll
    for(int i=0;i<EE;i++) v[i]=lg[i];
    int idx[KK]; float val[KK];
    #pragma unroll
    for(int k=0;k<KK;k++){
      float m=-1e30f; int mi=0;
      for(int i=0;i<EE;i++){ if(v[i]>m){ m=v[i]; mi=i; } }
      idx[k]=mi; val[k]=m; v[mi]=-1e30f;
    }
    float mx = val[0], s=0.f; float w[KK];
    #pragma unroll
    for(int k=0;k<KK;k++){ w[k]=__expf(val[k]-mx); s+=w[k]; }
    float inv = 1.f/s;
    #pragma unroll
    for(int k=0;k<KK;k++){ topk_idx[t*KK+k]=idx[k]; topk_w[t*KK+k]=w[k]*inv; }
    sig_gate[t] = 1.f/(1.f+__expf(-lg[EE]));
  }
}

// ---------------- per-expert token list (deterministic compaction) ----------
__global__ __launch_bounds__(64) void k_build(
    const int* __restrict__ topk_idx, const float* __restrict__ topk_w,
    int* __restrict__ token_list, float* __restrict__ weight_list,
    int* __restrict__ counts){
  int e = blockIdx.x; int l = threadIdx.x;
  int cnt = 0;
  for(int c=0;c<TT;c+=64){
    int t = c + l;
    int kk = -1;
    #pragma unroll
    for(int k=0;k<KK;k++) if(topk_idx[t*KK+k]==e) kk=k;
    unsigned long long b = __ballot(kk>=0);
    int pre = __popcll(b & ((1ull<<l)-1ull));
    if(kk>=0){
      token_list[e*TT + cnt + pre] = t;
      weight_list[e*TT + cnt + pre] = topk_w[t*KK+kk];
    }
    cnt += __popcll(b);
  }
  if(l==0) counts[e]=cnt;
}

// ---------------- LDS write helper: 4 bf16 (consecutive k, fixed n) ---------
__device__ __forceinline__ void wr4(unsigned short B[32][40], const float* f,
                                    int n, int ks){
  unsigned short u0=f2bf(f[0]), u1=f2bf(f[1]), u2=f2bf(f[2]), u3=f2bf(f[3]);
  uint2 v;
  v.x = (unsigned)u0 | ((unsigned)u1 << 16);
  v.y = (unsigned)u2 | ((unsigned)u3 << 16);
  *reinterpret_cast<uint2*>(&B[n][ks*4]) = v;
}

// Double-buffered dual-B GEMM: acc{g,u}[2] += A(64xK) * {Bg,Bu}(Kx32).
// Thread roles: A: row ar=tid>>2, 16B seg as_=tid&3 (advances 32 elems/step).
// B: col n=tid&31, k-seg ks=tid>>5 (4 strided dwords, advance 32*ldb/step).
__device__ __forceinline__ void gemm_dual32(
    const unsigned short* Ap, bool va,
    const float* Gp, const float* Up, int ldb, int NK,
    f32x4* ag, f32x4* au,
    unsigned short As[2][64][40], unsigned short Bg[2][32][40],
    unsigned short Bu[2][32][40], int tid){
  int w = tid>>6, l = tid&63;
  int n = tid&31, ks = tid>>5, ar = tid>>2, as_ = tid&3;
  uint4 av = make_uint4(0,0,0,0);
  float gv[4], uv[4];
  if(va) av = *reinterpret_cast<const uint4*>(Ap);
  #pragma unroll
  for(int i=0;i<4;i++){ gv[i]=Gp[(size_t)i*ldb]; uv[i]=Up[(size_t)i*ldb]; }
  *reinterpret_cast<uint4*>(&As[0][ar][as_*8]) = av;
  wr4(Bg[0], gv, n, ks); wr4(Bu[0], uv, n, ks);
  __syncthreads();
  for(int kk=0; kk<NK; kk++){
    int cur = kk & 1;
    bool more = (kk+1 < NK);
    if(more){
      av = make_uint4(0,0,0,0);
      if(va) av = *reinterpret_cast<const uint4*>(Ap + (size_t)(kk+1)*32);
      const float* g2 = Gp + (size_t)(kk+1)*32*ldb;
      const float* u2 = Up + (size_t)(kk+1)*32*ldb;
      #pragma unroll
      for(int i=0;i<4;i++){ gv[i]=g2[(size_t)i*ldb]; uv[i]=u2[(size_t)i*ldb]; }
    }
    int kt = l>>4, mm = l&15;
    s16x8 af = *reinterpret_cast<const s16x8*>(&As[cur][w*16+mm][kt*8]);
    #pragma unroll
    for(int c=0;c<2;c++){
      s16x8 b0 = *reinterpret_cast<const s16x8*>(&Bg[cur][c*16+mm][kt*8]);
      s16x8 b1 = *reinterpret_cast<const s16x8*>(&Bu[cur][c*16+mm][kt*8]);
      ag[c] = __builtin_amdgcn_mfma_f32_16x16x32_bf16(af, b0, ag[c], 0,0,0);
      au[c] = __builtin_amdgcn_mfma_f32_16x16x32_bf16(af, b1, au[c], 0,0,0);
    }
    if(more){
      int nx = cur^1;
      *reinterpret_cast<uint4*>(&As[nx][ar][as_*8]) = av;
      wr4(Bg[nx], gv, n, ks); wr4(Bu[nx], uv, n, ks);
    }
    __syncthreads();
  }
}

// Single-B variant.
__device__ __forceinline__ void gemm_single32(
    const unsigned short* Ap, bool va,
    const float* Bp, int ldb, int NK, f32x4* acc,
    unsigned short As[2][64][40], unsigned short Bs[2][32][40], int tid){
  int w = tid>>6, l = tid&63;
  int n = tid&31, ks = tid>>5, ar = tid>>2, as_ = tid&3;
  uint4 av = make_uint4(0,0,0,0);
  float bv[4];
  if(va) av = *reinterpret_cast<const uint4*>(Ap);
  #pragma unroll
  for(int i=0;i<4;i++) bv[i] = Bp[(size_t)i*ldb];
  *reinterpret_cast<uint4*>(&As[0][ar][as_*8]) = av;
  wr4(Bs[0], bv, n, ks);
  __syncthreads();
  for(int kk=0; kk<NK; kk++){
    int cur = kk & 1;
    bool more = (kk+1 < NK);
    if(more){
      av = make_uint4(0,0,0,0);
      if(va) av = *reinterpret_cast<const uint4*>(Ap + (size_t)(kk+1)*32);
      const float* b2 = Bp + (size_t)(kk+1)*32*ldb;
      #pragma unroll
      for(int i=0;i<4;i++) bv[i] = b2[(size_t)i*ldb];
    }
    int kt = l>>4, mm = l&15;
    s16x8 af = *reinterpret_cast<const s16x8*>(&As[cur][w*16+mm][kt*8]);
    #pragma unroll
    for(int c=0;c<2;c++){
      s16x8 b0 = *reinterpret_cast<const s16x8*>(&Bs[cur][c*16+mm][kt*8]);
      acc[c] = __builtin_amdgcn_mfma_f32_16x16x32_bf16(af, b0, acc[c], 0,0,0);
    }
    if(more){
      int nx = cur^1;
      *reinterpret_cast<uint4*>(&As[nx][ar][as_*8]) = av;
      wr4(Bs[nx], bv, n, ks);
    }
    __syncthreads();
  }
}

// ---------------- phase 2: ALL gate-up (shared + routed), N-tile = 32 -------
__global__ __launch_bounds__(256) void k_gateup_all(
    const unsigned short* __restrict__ xb,
    const float* __restrict__ Wsg, const float* __restrict__ Wsu,
    unsigned short* __restrict__ Hs,
    const float* __restrict__ Wgate, const float* __restrict__ Wup,
    const int* __restrict__ token_list, const int* __restrict__ counts,
    unsigned short* __restrict__ hbuf){
  __shared__ unsigned short As[2][64][40];
  __shared__ unsigned short Bg[2][32][40];
  __shared__ unsigned short Bu[2][32][40];
  int tid = threadIdx.x, w = tid>>6, l = tid&63;
  int n = tid&31, ks = tid>>5, ar = tid>>2, as_ = tid&3;
  int bid = blockIdx.x;
  f32x4 zero = {0.f,0.f,0.f,0.f};
  const int NSH = (SS/32)*(TT/64);   // 512 shared blocks

  if(bid < NSH){
    int n0 = (bid & (SS/32 - 1)) * 32;
    int r0 = (bid >> 6) * 64;
    f32x4 ag[2]={zero,zero}, au[2]={zero,zero};
    const unsigned short* Ap = xb + (size_t)(r0+ar)*HH + as_*8;
    const float* Gp = Wsg + (size_t)(ks*4)*SS + n0 + n;
    const float* Up = Wsu + (size_t)(ks*4)*SS + n0 + n;
    gemm_dual32(Ap, true, Gp, Up, SS, HH/32, ag, au, As, Bg, Bu, tid);
    int mm = l&15, rb = r0 + w*16 + (l>>4)*4;
    #pragma unroll
    for(int c=0;c<2;c++){
      #pragma unroll
      for(int j=0;j<4;j++){
        float g = ag[c][j], u = au[c][j];
        Hs[(size_t)(rb+j)*SS + n0 + c*16 + mm] = f2bf(g*u/(1.f+__expf(-g)));
      }
    }
  } else {
    int b = bid - NSH;
    int e = b >> 4;            // II/32 = 16 tiles per expert
    int i0 = (b & 15) * 32;
    int cnt = counts[e]; if(cnt == 0) return;
    int off = 0;
    for(int i=0;i<e;i++) off += counts[i];
    const float* Bg0 = Wgate + (size_t)e*HH*II;
    const float* Bu0 = Wup   + (size_t)e*HH*II;
    for(int rt=0; rt*64<cnt; rt++){
      int nv = cnt - rt*64; if(nv > 64) nv = 64;
      const int* rows = token_list + e*TT + rt*64;
      int arow = (ar < nv) ? rows[ar] : 0;
      bool va = ar < nv;
      f32x4 ag[2]={zero,zero}, au[2]={zero,zero};
      const unsigned short* Ap = xb + (size_t)arow*HH + as_*8;
      const float* Gp = Bg0 + (size_t)(ks*4)*II + i0 + n;
      const float* Up = Bu0 + (size_t)(ks*4)*II + i0 + n;
      gemm_dual32(Ap, va, Gp, Up, II, HH/32, ag, au, As, Bg, Bu, tid);
      int mm = l&15, rr0 = w*16 + (l>>4)*4;
      #pragma unroll
      for(int c=0;c<2;c++){
        #pragma unroll
        for(int j=0;j<4;j++){
          int rr = rr0 + j;
          if(rr < nv){
            float g = ag[c][j], u = au[c][j];
            hbuf[(size_t)(off+rt*64+rr)*II + i0 + c*16 + mm] =
                f2bf(g*u/(1.f+__expf(-g)));
          }
        }
      }
    }
  }
}

// ---------------- phase 3: ALL down (shared + routed), N-tile = 32 ----------
__global__ __launch_bounds__(256) void k_down_all(
    const unsigned short* __restrict__ Hsrc, const float* __restrict__ Wsd,
    const float* __restrict__ sig_gate,
    const unsigned short* __restrict__ hbuf, const float* __restrict__ Wdown,
    const int* __restrict__ token_list, const float* __restrict__ weight_list,
    const int* __restrict__ counts, float* __restrict__ out){
  __shared__ unsigned short As[2][64][40];
  __shared__ unsigned short Bs[2][32][40];
  int tid = threadIdx.x, w = tid>>6, l = tid&63;
  int n = tid&31, ks = tid>>5, ar = tid>>2, as_ = tid&3;
  int bid = blockIdx.x;
  f32x4 zero = {0.f,0.f,0.f,0.f};
  const int NSH = (HH/32)*(TT/64);   // 256 shared blocks

  if(bid < NSH){
    int n0 = (bid & (HH/32 - 1)) * 32;
    int r0 = (bid >> 5) * 64;
    f32x4 acc[2]={zero,zero};
    const unsigned short* Ap = Hsrc + (size_t)(r0+ar)*SS + as_*8;
    const float* Bp = Wsd + (size_t)(ks*4)*HH + n0 + n;
    gemm_single32(Ap, true, Bp, HH, SS/32, acc, As, Bs, tid);
    int mm = l&15, rb = r0 + w*16 + (l>>4)*4;
    #pragma unroll
    for(int c=0;c<2;c++){
      #pragma unroll
      for(int j=0;j<4;j++){
        atomicAdd(&out[(size_t)(rb+j)*HH + n0 + c*16 + mm],
                  sig_gate[rb+j]*acc[c][j]);
      }
    }
  } else {
    int b = bid - NSH;
    int e = b >> 5;            // HH/32 = 32 tiles per expert
    int n0 = (b & 31) * 32;
    int cnt = counts[e]; if(cnt == 0) return;
    int off = 0;
    for(int i=0;i<e;i++) off += counts[i];
    const float* B0 = Wdown + (size_t)e*II*HH;
    for(int rt=0; rt*64<cnt; rt++){
      int nv = cnt - rt*64; if(nv > 64) nv = 64;
      bool va = ar < nv;
      f32x4 acc[2]={zero,zero};
      const unsigned short* Ap = hbuf + (size_t)(off+rt*64+ar)*II + as_*8;
      const float* Bp = B0 + (size_t)(ks*4)*HH + n0 + n;
      gemm_single32(Ap, va, Bp, HH, II/32, acc, As, Bs, tid);
      int mm = l&15, rr0 = w*16 + (l>>4)*4;
      #pragma unroll
      for(int c=0;c<2;c++){
        #pragma unroll
        for(int j=0;j<4;j++){
          int rr = rr0 + j;
          if(rr < nv){
            int t = token_list[e*TT + rt*64 + rr];
            float wt = weight_list[e*TT + rt*64 + rr];
            atomicAdd(&out[(size_t)t*HH + n0 + c*16 + mm], wt*acc[c][j]);
          }
        }
      }
    }
  }
}

extern "C" void kernel_launch(void* const* d_in, const int* in_sizes, int n_in,
                              void* d_out, int out_size, void* d_ws, size_t ws_size,
                              hipStream_t stream) {
  const float* x     = (const float*)d_in[0];
  const float* Wg    = (const float*)d_in[1];
  const float* Wgate = (const float*)d_in[2];
  const float* Wup   = (const float*)d_in[3];
  const float* Wdown = (const float*)d_in[4];
  const float* Wsg   = (const float*)d_in[5];
  const float* Wsu   = (const float*)d_in[6];
  const float* Wsd   = (const float*)d_in[7];
  float* out = (float*)d_out;

  char* ws = (char*)d_ws;
  unsigned short* xb   = (unsigned short*)ws; ws += (size_t)TT*HH*2;
  unsigned short* Hs   = (unsigned short*)ws; ws += (size_t)TT*SS*2;
  unsigned short* hbuf = (unsigned short*)ws; ws += (size_t)(TT*KK+64)*II*2;
  int*   token_list  = (int*)ws;   ws += (size_t)EE*TT*4;
  float* weight_list = (float*)ws; ws += (size_t)EE*TT*4;
  int*   topk_idx    = (int*)ws;   ws += (size_t)TT*KK*4;
  float* topk_wq     = (float*)ws; ws += (size_t)TT*KK*4;
  int*   counts      = (int*)ws;   ws += 128;
  float* sig_gate    = (float*)ws; ws += (size_t)TT*4;

  hipMemsetAsync(d_out, 0, (size_t)TT*HH*4, stream);
  k_router<<<TT, 64, 0, stream>>>(x, Wg, xb, topk_idx, topk_wq, sig_gate);
  k_build<<<EE, 64, 0, stream>>>(topk_idx, topk_wq, token_list, weight_list, counts);
  k_gateup_all<<<(SS/32)*(TT/64) + EE*(II/32), 256, 0, stream>>>(
      xb, Wsg, Wsu, Hs, Wgate, Wup, token_list, counts, hbuf);
  k_down_all<<<(HH/32)*(TT/64) + EE*(HH/32), 256, 0, stream>>>(
      Hs, Wsd, sig_gate, hbuf, Wdown, token_list, weight_list, counts, out);
}